// Round 12
// baseline (768.167 us; speedup 1.0000x reference)
//
#include <hip/hip_runtime.h>
#include <hip/hip_cooperative_groups.h>

namespace cg = cooperative_groups;

// ---------------------------------------------------------------------------
// 2-layer GAT (PyG GATConv), MI355X — single cooperative kernel.
// Verified semantics (r8-r11): A=int32 on device (dual-path kept), floats=f32,
// out=f32; dropout = threefry-partitionable 32-bit: bits = x0^x1 of
// threefry2x32(key=(0,42), ctr=(0,i)); u=(bits>>9)|0x3f800000; keep u-1<0.7f.
// Phases: detect | P0 zero+convert | P1 count||gemm1 | P2 scan(2-level) |
//         P3 fill | P4 agg1(+dropout) | P5 gemm2 | P6 agg2.
// ---------------------------------------------------------------------------

__device__ __forceinline__ unsigned rotl32(unsigned x, unsigned r) {
  return (x << r) | (x >> (32u - r));
}

__device__ __forceinline__ void threefry2_0_42(unsigned c0, unsigned c1,
                                               unsigned* o0, unsigned* o1) {
  const unsigned k0 = 0u, k1 = 42u;
  const unsigned k2 = k0 ^ k1 ^ 0x1BD11BDAu;
  unsigned ks[3] = {k0, k1, k2};
  unsigned x0 = c0 + ks[0];
  unsigned x1 = c1 + ks[1];
  const unsigned R[2][4] = {{13u, 15u, 26u, 6u}, {17u, 29u, 16u, 24u}};
#pragma unroll
  for (int i = 0; i < 5; ++i) {
#pragma unroll
    for (int j = 0; j < 4; ++j) {
      unsigned r = R[i & 1][j];
      x0 += x1;
      x1 = rotl32(x1, r);
      x1 ^= x0;
    }
    x0 += ks[(i + 1) % 3];
    x1 += ks[(i + 2) % 3] + (unsigned)(i + 1);
  }
  *o0 = x0;
  *o1 = x1;
}

__device__ __forceinline__ float ldf(const void* p, int isbf, size_t i) {
  if (isbf) {
    unsigned short u = ((const unsigned short*)p)[i];
    return __uint_as_float(((unsigned)u) << 16);
  }
  return ((const float*)p)[i];
}

// exclusive scan of v over 256 threads; returns (excl, blockTotal)
__device__ __forceinline__ void block_scan256(int v, int t, int* wpre,
                                              int* exclOut, int* totOut) {
  int lane = t & 63, w = t >> 6;
  int inc = v;
#pragma unroll
  for (int d = 1; d < 64; d <<= 1) {
    int o = __shfl_up(inc, d);
    if (lane >= d) inc += o;
  }
  if (lane == 63) wpre[w] = inc;
  __syncthreads();
  int wp = 0, tot = 0;
#pragma unroll
  for (int j = 0; j < 4; ++j) {
    int s = wpre[j];
    if (j < w) wp += s;
    tot += s;
  }
  __syncthreads();
  *exclOut = wp + inc - v;
  *totOut = tot;
}

// 64x64 register-tiled GEMM over tiles [bid0, gTile) stride gstride.
// k-split into 2 chunks of 32 (LDS 17KB).
__device__ void gemm_phase(const void* __restrict__ X, int isbf,
                           const float* __restrict__ Wc,
                           const float* __restrict__ a_src,
                           const float* __restrict__ a_dst,
                           float* __restrict__ H, float* __restrict__ ssrc,
                           float* __restrict__ sdst, int n, int bid0,
                           int gstride, int t, float* Xt, float* Ws) {
  const int gTile = (n + 63) >> 6;
  int r0 = (t >> 4) * 4;
  int c0 = (t & 15) * 4;
  for (int tile = bid0; tile < gTile; tile += gstride) {
    int row0 = tile * 64;
    float acc[4][4];
#pragma unroll
    for (int r = 0; r < 4; ++r)
#pragma unroll
      for (int c = 0; c < 4; ++c) acc[r][c] = 0.f;

#pragma unroll
    for (int chunk = 0; chunk < 2; ++chunk) {
      int kbase = chunk * 32;
      // stage W chunk: [32][64]
#pragma unroll
      for (int i = t; i < 512; i += 256) {
        int k = i >> 4, jq = i & 15;
        *(float4*)&Ws[k * 64 + jq * 4] =
            *(const float4*)&Wc[(kbase + k) * 64 + jq * 4];
      }
      // stage X chunk transposed: Xt[k][row], rows 0..63, k 0..31
#pragma unroll
      for (int i = t; i < 512; i += 256) {
        int r = i >> 3, q = i & 7;
        int row = row0 + r;
        float4 v = {0.f, 0.f, 0.f, 0.f};
        if (row < n) {
          if (isbf) {
            v.x = ldf(X, 1, (size_t)row * 64 + kbase + q * 4 + 0);
            v.y = ldf(X, 1, (size_t)row * 64 + kbase + q * 4 + 1);
            v.z = ldf(X, 1, (size_t)row * 64 + kbase + q * 4 + 2);
            v.w = ldf(X, 1, (size_t)row * 64 + kbase + q * 4 + 3);
          } else {
            v = *(const float4*)&((const float*)X)[(size_t)row * 64 + kbase +
                                                   q * 4];
          }
        }
        Xt[(q * 4 + 0) * 68 + r] = v.x;
        Xt[(q * 4 + 1) * 68 + r] = v.y;
        Xt[(q * 4 + 2) * 68 + r] = v.z;
        Xt[(q * 4 + 3) * 68 + r] = v.w;
      }
      __syncthreads();
#pragma unroll 8
      for (int k = 0; k < 32; ++k) {
        float4 a4 = *(const float4*)&Xt[k * 68 + r0];
        float4 b4 = *(const float4*)&Ws[k * 64 + c0];
        const float av[4] = {a4.x, a4.y, a4.z, a4.w};
        const float bv[4] = {b4.x, b4.y, b4.z, b4.w};
#pragma unroll
        for (int r = 0; r < 4; ++r)
#pragma unroll
          for (int c = 0; c < 4; ++c)
            acc[r][c] = fmaf(av[r], bv[c], acc[r][c]);
      }
      __syncthreads();
    }

    // scores: reduce per-thread 4-col partials across the 16 col groups
    const float4 asr = *(const float4*)&a_src[c0];
    const float4 adr = *(const float4*)&a_dst[c0];
#pragma unroll
    for (int r = 0; r < 4; ++r) {
      float vs = acc[r][0] * asr.x + acc[r][1] * asr.y + acc[r][2] * asr.z +
                 acc[r][3] * asr.w;
      float vd = acc[r][0] * adr.x + acc[r][1] * adr.y + acc[r][2] * adr.z +
                 acc[r][3] * adr.w;
#pragma unroll
      for (int d = 1; d < 16; d <<= 1) {
        vs += __shfl_xor(vs, d);
        vd += __shfl_xor(vd, d);
      }
      int row = row0 + r0 + r;
      if ((t & 15) == 0 && row < n) {
        ssrc[row] = vs;
        sdst[row] = vd;
      }
    }
#pragma unroll
    for (int r = 0; r < 4; ++r) {
      int row = row0 + r0 + r;
      if (row < n) {
        float4 o = {acc[r][0], acc[r][1], acc[r][2], acc[r][3]};
        *(float4*)&H[(size_t)row * 64 + c0] = o;
      }
    }
  }
}

#define AGG_STEP(IDX, ACC)                                              \
  {                                                                     \
    int idx_ = (IDX);                                                   \
    float cl_ = __shfl(c, idx_);                                        \
    int sr_ = __shfl(sl, idx_);                                         \
    if (idx_ < glim) {                                                  \
      const float4 hv_ = *(const float4*)&h[(size_t)sr_ * 64 + f4 * 4]; \
      ACC.x = fmaf(cl_, hv_.x, ACC.x);                                  \
      ACC.y = fmaf(cl_, hv_.y, ACC.y);                                  \
      ACC.z = fmaf(cl_, hv_.z, ACC.z);                                  \
      ACC.w = fmaf(cl_, hv_.w, ACC.w);                                  \
    }                                                                   \
  }

template <int DROPOUT>
__device__ void agg_phase(const float* __restrict__ h,
                          const float* __restrict__ ssrc,
                          const float* __restrict__ sdst,
                          const float* __restrict__ bias,
                          const int* __restrict__ offsets,
                          const int* __restrict__ csr,
                          float* __restrict__ alphaE, float* __restrict__ out,
                          int n, int bid, int G, int t) {
  int lane = t & 63;
  int e4 = lane >> 4, f4 = lane & 15;
  for (int wid = bid * 4 + (t >> 6); wid < n; wid += G * 4) {
    int off = offsets[wid];
    int end = offsets[wid + 1];
    int g = end - off;
    float sd = sdst[wid];
    float4 acc0 = {0.f, 0.f, 0.f, 0.f}, acc1 = {0.f, 0.f, 0.f, 0.f};

    if (g <= 64) {
      int sl = 0;
      float v = -1e30f;
      if (lane < g) {
        sl = csr[off + lane];
        float tv = ssrc[sl] + sd;
        v = (tv > 0.f) ? tv : 0.2f * tv;
      }
      float m = v;
#pragma unroll
      for (int d = 32; d; d >>= 1) m = fmaxf(m, __shfl_xor(m, d));
      float ex = (lane < g) ? __expf(v - m) : 0.f;
      float s = ex;
#pragma unroll
      for (int d = 32; d; d >>= 1) s += __shfl_xor(s, d);
      float c = ex * (1.f / s);
      int glim = g;
      for (int cb = 0; cb < g; cb += 8) {
        AGG_STEP(cb + e4, acc0)
        AGG_STEP(cb + 4 + e4, acc1)
      }
    } else {
      float mm = -1e30f, ss = 0.f;
      for (int e = off + lane; e < end; e += 64) {
        int sl2 = csr[e];
        float tv = ssrc[sl2] + sd;
        tv = (tv > 0.f) ? tv : 0.2f * tv;
        alphaE[e] = tv;
        float mn = fmaxf(mm, tv);
        ss = ss * __expf(mm - mn) + __expf(tv - mn);
        mm = mn;
      }
#pragma unroll
      for (int d = 32; d; d >>= 1) {
        float mo = __shfl_xor(mm, d);
        float so = __shfl_xor(ss, d);
        float mn = fmaxf(mm, mo);
        ss = ss * __expf(mm - mn) + so * __expf(mo - mn);
        mm = mn;
      }
      float inv = 1.f / ss;
      for (int base = off; base < end; base += 64) {
        int e = base + lane;
        int cnt = min(64, end - base);
        float c = 0.f;
        int sl = 0;
        if (e < end) {
          c = __expf(alphaE[e] - mm) * inv;
          sl = csr[e];
        }
        int glim = cnt;
        for (int cb = 0; cb < cnt; cb += 8) {
          AGG_STEP(cb + e4, acc0)
          AGG_STEP(cb + 4 + e4, acc1)
        }
      }
    }

    float4 r;
    r.x = acc0.x + acc1.x;
    r.y = acc0.y + acc1.y;
    r.z = acc0.z + acc1.z;
    r.w = acc0.w + acc1.w;
#pragma unroll
    for (int d = 16; d < 64; d <<= 1) {
      r.x += __shfl_xor(r.x, d);
      r.y += __shfl_xor(r.y, d);
      r.z += __shfl_xor(r.z, d);
      r.w += __shfl_xor(r.w, d);
    }

    unsigned long long mask = 0ull;
    if (DROPOUT) {
      unsigned i0 = (unsigned)wid * 64u + (unsigned)lane;
      unsigned o0, o1;
      threefry2_0_42(0u, i0, &o0, &o1);
      unsigned bits = o0 ^ o1;
      float u = __uint_as_float((bits >> 9) | 0x3f800000u) - 1.0f;
      mask = __ballot(u < 0.7f);
    }

    if (lane < 16) {
      const float4 b4 = *(const float4*)&bias[lane * 4];
      r.x = fmaxf(r.x + b4.x, 0.f);
      r.y = fmaxf(r.y + b4.y, 0.f);
      r.z = fmaxf(r.z + b4.z, 0.f);
      r.w = fmaxf(r.w + b4.w, 0.f);
      if (DROPOUT) {
        r.x = ((mask >> (lane * 4 + 0)) & 1ull) ? r.x / 0.7f : 0.f;
        r.y = ((mask >> (lane * 4 + 1)) & 1ull) ? r.y / 0.7f : 0.f;
        r.z = ((mask >> (lane * 4 + 2)) & 1ull) ? r.z / 0.7f : 0.f;
        r.w = ((mask >> (lane * 4 + 3)) & 1ull) ? r.w / 0.7f : 0.f;
      }
      *(float4*)&out[(size_t)wid * 64 + lane * 4] = r;
    }
  }
}

__global__ __launch_bounds__(256) void k_gat(
    const void* E, const void* A, const void* W1, const void* as1,
    const void* ad1, const void* b1, const void* W2, const void* as2,
    const void* ad2, const void* b2, float* h, float* x1, float* ssrc,
    float* sdst, float* alphaE, float* smallc, int* deg, int* offsets,
    int* cursor, int* chunkSum, int* csr, float* outp, int N, int Eb) {
  cg::grid_group grid = cg::this_grid();
  __shared__ float Xt[32 * 68];
  __shared__ float Ws[32 * 64];
  __shared__ int wpre[4];
  __shared__ int chunkPreLds[256];
  __shared__ int s_flags[2];

  const int t = threadIdx.x;
  const int bid = blockIdx.x;
  const int G = gridDim.x;
  const int Etot = Eb + N;
  const int nChunks = (N + 255) >> 8;

  // ---- block-local dtype detection ----
  if (t == 0) {
    s_flags[0] = 1;
    s_flags[1] = 0;
  }
  __syncthreads();
  {
    long long v = ((const long long*)A)[t];
    if (!(v >= 0 && v < (long long)N)) atomicAnd(&s_flags[0], 0);
    unsigned w = ((const unsigned*)E)[t];
    unsigned b = (w >> 8) & 0x7F;
    if (b >= 0x3A && b <= 0x43) atomicAdd(&s_flags[1], 1);
  }
  __syncthreads();
  const int is64 = s_flags[0];
  const int isbf = (s_flags[1] >= 200) ? 1 : 0;
  const int* A32 = (const int*)A;
  const long long* A64 = (const long long*)A;

  // ---- P0: zero deg/cursor/chunkSum + convert small tensors ----
  for (int i = bid * 256 + t; i < N; i += G * 256) {
    deg[i] = 0;
    cursor[i] = 0;
  }
  if (bid == 0) chunkSum[t] = 0;
  for (int i = bid * 256 + t; i < 8576; i += G * 256) {
    float x;
    if (i < 4096) x = ldf(W1, isbf, i);
    else if (i < 4160) x = ldf(as1, isbf, i - 4096);
    else if (i < 4224) x = ldf(ad1, isbf, i - 4160);
    else if (i < 4288) x = ldf(b1, isbf, i - 4224);
    else if (i < 8384) x = ldf(W2, isbf, i - 4288);
    else if (i < 8448) x = ldf(as2, isbf, i - 8384);
    else if (i < 8512) x = ldf(ad2, isbf, i - 8448);
    else x = ldf(b2, isbf, i - 8512);
    smallc[i] = x;
  }
  grid.sync();

  // ---- P1: count (most blocks) || gemm1 (first gemmShare blocks) ----
  {
    int gemmShare = G / 3;
    if (gemmShare < 1) gemmShare = 1;
    if (bid < gemmShare) {
      gemm_phase(E, isbf, smallc, smallc + 4096, smallc + 4160, h, ssrc, sdst,
                 N, bid, gemmShare, t, Xt, Ws);
    } else {
      int nb = G - gemmShare;
      for (int e = (bid - gemmShare) * 256 + t; e < Eb; e += nb * 256) {
        int d = is64 ? (int)A64[(long long)Eb + e] : A32[Eb + e];
        atomicAdd(&deg[d], 1);
      }
    }
  }
  grid.sync();

  // ---- P2a: per-chunk exclusive scans ----
  for (int c = bid; c < nChunks; c += G) {
    int i = c * 256 + t;
    int adj = (i < N) ? deg[i] + 1 : 0;  // +1 = self-loop
    int excl, tot;
    block_scan256(adj, t, wpre, &excl, &tot);
    if (i < N) offsets[i] = excl;
    if (t == 255) chunkSum[c] = tot;
  }
  grid.sync();

  // ---- P2c: all blocks redundantly scan chunk sums, then add prefixes ----
  {
    int cs = chunkSum[t];  // t < 256, zero-padded past nChunks
    int excl, tot;
    block_scan256(cs, t, wpre, &excl, &tot);
    chunkPreLds[t] = excl;
    __syncthreads();
    for (int i = bid * 256 + t; i < N; i += G * 256)
      offsets[i] += chunkPreLds[i >> 8];
    if (bid == 0 && t == 0) offsets[N] = Etot;
  }
  grid.sync();

  // ---- P3: fill CSR ----
  for (int e = bid * 256 + t; e < Etot; e += G * 256) {
    int s, d;
    if (e < Eb) {
      if (is64) {
        s = (int)A64[e];
        d = (int)A64[(long long)Eb + e];
      } else {
        s = A32[e];
        d = A32[Eb + e];
      }
    } else {
      s = d = e - Eb;
    }
    int slot = atomicAdd(&cursor[d], 1);
    csr[offsets[d] + slot] = s;
  }
  grid.sync();

  // ---- P4: aggregate layer 1 (+relu+dropout) ----
  agg_phase<1>(h, ssrc, sdst, smallc + 4224, offsets, csr, alphaE, x1, N, bid,
               G, t);
  grid.sync();

  // ---- P5: gemm layer 2 ----
  gemm_phase(x1, 0, smallc + 4288, smallc + 8384, smallc + 8448, h, ssrc, sdst,
             N, bid, G, t, Xt, Ws);
  grid.sync();

  // ---- P6: aggregate layer 2 (+relu) ----
  agg_phase<0>(h, ssrc, sdst, smallc + 8512, offsets, csr, alphaE, outp, N,
               bid, G, t);
}

extern "C" void kernel_launch(void* const* d_in, const int* in_sizes, int n_in,
                              void* d_out, int out_size, void* d_ws, size_t ws_size,
                              hipStream_t stream) {
  const void* E = d_in[0];
  const void* A = d_in[1];
  const void* W1 = d_in[2];
  const void* as1 = d_in[3];
  const void* ad1 = d_in[4];
  const void* b1 = d_in[5];
  const void* W2 = d_in[6];
  const void* as2 = d_in[7];
  const void* ad2 = d_in[8];
  const void* b2 = d_in[9];
  float* outp = (float*)d_out;

  int N = in_sizes[0] / 64;   // 50000
  int Eb = in_sizes[1] / 2;   // 800000
  const int Etot = Eb + N;
  const int total = N * 64;

  float* ws = (float*)d_ws;
  float* h = ws;                          // total
  float* x1 = h + (size_t)total;          // total
  float* ssrc = x1 + (size_t)total;       // N
  float* sdst = ssrc + N;                 // N
  float* alphaE = sdst + N;               // Etot
  float* smallc = alphaE + Etot;          // 8576
  int* deg = (int*)(smallc + 8576);       // N
  int* offsets = deg + N;                 // N+1
  int* cursor = offsets + (N + 1);        // N
  int* chunkSum = cursor + N;             // 256
  int* csr = chunkSum + 256;              // Etot

  int numCU = 256;
  hipDeviceGetAttribute(&numCU, hipDeviceAttributeMultiprocessorCount, 0);
  int maxB = 0;
  if (hipOccupancyMaxActiveBlocksPerMultiprocessor(&maxB, k_gat, 256,
                                                   (size_t)0) != hipSuccess ||
      maxB < 1)
    maxB = 4;
  int G = numCU * maxB;

  void* args[] = {&E,      &A,      &W1,     &as1,    &ad1,      &b1,
                  &W2,     &as2,    &ad2,    &b2,     &h,        &x1,
                  &ssrc,   &sdst,   &alphaE, &smallc, &deg,      &offsets,
                  &cursor, &chunkSum, &csr,  &outp,   &N,        &Eb};
  hipLaunchCooperativeKernel((void*)k_gat, dim3(G), dim3(256), args, 0,
                             stream);
}